// Round 2
// baseline (148.244 us; speedup 1.0000x reference)
//
#include <hip/hip_runtime.h>
#include <math.h>

// PointWarping: B=4, C=3, N=8192 fp32 brute-force 3-NN + IDW flow warp.
// Structure: block = 256 threads = 4 waves. Each wave owns 8 wave-uniform
// queries (coeffs in SGPRs); its 64 lanes scan the DB interleaved
// (lane + 64*j) so ds_read_b128 is conflict-free. Branchless top-3 via
// v_med3_f32 + cndmask. Butterfly shuffle merge across the wave.

#define NTHREADS 256
#define TILE 1024
#define QPW 8                      // queries per wave
#define QPB 32                     // queries per block (4 waves)

__device__ __forceinline__ void ins3(float& a0, float& a1, float& a2,
                                     int& j0, int& j1, int& j2,
                                     float bm, int bi) {
  // lexicographic (m, idx) insert of one entry into sorted triple
  const bool c0 = (bm < a0) || (bm == a0 && bi < j0);
  const bool c1 = (bm < a1) || (bm == a1 && bi < j1);
  const bool c2 = (bm < a2) || (bm == a2 && bi < j2);
  const float t0 = a0, t1 = a1;
  const int u0 = j0, u1 = j1;
  a0 = c0 ? bm : a0;
  a1 = c0 ? t0 : (c1 ? bm : a1);
  a2 = c1 ? t1 : (c2 ? bm : a2);
  j0 = c0 ? bi : j0;
  j1 = c0 ? u0 : (c1 ? bi : j1);
  j2 = c1 ? u1 : (c2 ? bi : j2);
}

__global__ __launch_bounds__(NTHREADS) void pointwarp_kernel(
    const float* __restrict__ pos1,
    const float* __restrict__ pos2,
    const float* __restrict__ flow1,
    float* __restrict__ out,
    int N) {
  const int b = blockIdx.y;
  const int qbase = blockIdx.x * QPB;
  const int tid = threadIdx.x;
  const int lane = tid & 63;
  const int wav = tid >> 6;  // 0..3: which query-octet this wave owns

  const float* p1 = pos1 + (size_t)b * 3 * N;
  const float* p2 = pos2 + (size_t)b * 3 * N;
  const float* f1 = flow1 + (size_t)b * 3 * N;

  // wave-uniform query coefficients -> SGPRs.  metric m = |k|^2 - 2 q.k
  float na[QPW], nb_[QPW], nc[QPW];
#pragma unroll
  for (int r = 0; r < QPW; ++r) {
    const int qi = qbase + wav * QPW + r;
    na[r] = __int_as_float(__builtin_amdgcn_readfirstlane(__float_as_int(-2.0f * p2[qi])));
    nb_[r] = __int_as_float(__builtin_amdgcn_readfirstlane(__float_as_int(-2.0f * p2[N + qi])));
    nc[r] = __int_as_float(__builtin_amdgcn_readfirstlane(__float_as_int(-2.0f * p2[2 * N + qi])));
  }

  __shared__ float4 tile[TILE];  // {kx,ky,kz,|k|^2}
  __shared__ int finals[QPB][3];

  float m0[QPW], m1[QPW], m2[QPW];
  int i0[QPW], i1[QPW], i2[QPW];
#pragma unroll
  for (int r = 0; r < QPW; ++r) {
    m0[r] = INFINITY; m1[r] = INFINITY; m2[r] = INFINITY;
    i0[r] = 0; i1[r] = 0; i2[r] = 0;
  }

  for (int t = 0; t < N; t += TILE) {
    __syncthreads();
#pragma unroll
    for (int u = 0; u < TILE / NTHREADS; ++u) {
      const int j = u * NTHREADS + tid;
      const int g = t + j;
      const float kx = p1[g] + f1[g];
      const float ky = p1[N + g] + f1[N + g];
      const float kz = p1[2 * N + g] + f1[2 * N + g];
      tile[j] = make_float4(kx, ky, kz, fmaf(kx, kx, fmaf(ky, ky, kz * kz)));
    }
    __syncthreads();

#pragma unroll 4
    for (int j = 0; j < TILE / 64; ++j) {
      const float4 k = tile[j * 64 + lane];
      const int idx = t + j * 64 + lane;
#pragma unroll
      for (int r = 0; r < QPW; ++r) {
        const float m = fmaf(na[r], k.x, fmaf(nb_[r], k.y, fmaf(nc[r], k.z, k.w)));
        // branchless sorted top-3 (strict <; idx ascending => stable ties)
        const bool c0 = m < m0[r];
        const bool c1 = m < m1[r];
        const bool c2 = m < m2[r];
        const float om0 = m0[r], om1 = m1[r];
        m0[r] = fminf(m, om0);
        m1[r] = __builtin_amdgcn_fmed3f(m, om0, om1);
        m2[r] = __builtin_amdgcn_fmed3f(m, om1, m2[r]);
        const int oi0 = i0[r], oi1 = i1[r];
        i2[r] = c1 ? oi1 : (c2 ? idx : i2[r]);
        i1[r] = c0 ? oi0 : (c1 ? idx : i1[r]);
        i0[r] = c0 ? idx : oi0;
      }
    }
  }

  // butterfly merge across the 64 lanes of the wave
#pragma unroll
  for (int mask = 32; mask >= 1; mask >>= 1) {
#pragma unroll
    for (int r = 0; r < QPW; ++r) {
      const float bm0 = __shfl_xor(m0[r], mask, 64);
      const float bm1 = __shfl_xor(m1[r], mask, 64);
      const float bm2 = __shfl_xor(m2[r], mask, 64);
      const int bi0 = __shfl_xor(i0[r], mask, 64);
      const int bi1 = __shfl_xor(i1[r], mask, 64);
      const int bi2 = __shfl_xor(i2[r], mask, 64);
      ins3(m0[r], m1[r], m2[r], i0[r], i1[r], i2[r], bm0, bi0);
      ins3(m0[r], m1[r], m2[r], i0[r], i1[r], i2[r], bm1, bi1);
      ins3(m0[r], m1[r], m2[r], i0[r], i1[r], i2[r], bm2, bi2);
    }
  }

  if (lane == 0) {
#pragma unroll
    for (int r = 0; r < QPW; ++r) {
      const int q = wav * QPW + r;
      finals[q][0] = i0[r];
      finals[q][1] = i1[r];
      finals[q][2] = i2[r];
    }
  }
  __syncthreads();

  if (tid < QPB) {
    const int qi = qbase + tid;
    const float qx = p2[qi];
    const float qy = p2[N + qi];
    const float qz = p2[2 * N + qi];

    float w[3], gfx[3], gfy[3], gfz[3];
    float wsum = 0.0f;
#pragma unroll
    for (int r = 0; r < 3; ++r) {
      const int idx = finals[tid][r];
      const float fx = f1[idx], fy = f1[N + idx], fz = f1[2 * N + idx];
      const float kx = p1[idx] + fx;
      const float ky = p1[N + idx] + fy;
      const float kz = p1[2 * N + idx] + fz;
      const float dx = kx - qx, dy = ky - qy, dz = kz - qz;
      float d = sqrtf(dx * dx + dy * dy + dz * dz);
      d = fmaxf(d, 1e-10f);
      const float inv = 1.0f / d;
      w[r] = inv; wsum += inv;
      gfx[r] = fx; gfy[r] = fy; gfz[r] = fz;
    }
    const float invw = 1.0f / wsum;
    float ox = 0.0f, oy = 0.0f, oz = 0.0f;
#pragma unroll
    for (int r = 0; r < 3; ++r) {
      const float ww = w[r] * invw;
      ox = fmaf(ww, gfx[r], ox);
      oy = fmaf(ww, gfy[r], oy);
      oz = fmaf(ww, gfz[r], oz);
    }
    ox = qx - ox; oy = qy - oy; oz = qz - oz;
    ox = fminf(fmaxf(ox, -10.0f), 10.0f);
    oy = fminf(fmaxf(oy, -10.0f), 10.0f);
    oz = fminf(fmaxf(oz, -10.0f), 10.0f);
    float* o = out + (size_t)b * 3 * N;
    o[qi] = ox;
    o[N + qi] = oy;
    o[2 * N + qi] = oz;
  }
}

extern "C" void kernel_launch(void* const* d_in, const int* in_sizes, int n_in,
                              void* d_out, int out_size, void* d_ws, size_t ws_size,
                              hipStream_t stream) {
  const float* pos1 = (const float*)d_in[0];
  const float* pos2 = (const float*)d_in[1];
  const float* flow1 = (const float*)d_in[2];
  float* out = (float*)d_out;

  const int B = 4;
  const int N = in_sizes[0] / (B * 3);  // 8192

  dim3 grid(N / QPB, B);
  dim3 block(NTHREADS);
  pointwarp_kernel<<<grid, block, 0, stream>>>(pos1, pos2, flow1, out, N);
}

// Round 3
// 81.595 us; speedup vs baseline: 1.8168x; 1.8168x over previous
//
#include <hip/hip_runtime.h>
#include <math.h>

// PointWarping: B=4, C=3, N=8192 fp32 brute-force 3-NN + IDW flow warp.
// Block = 256 threads = 4 waves; each wave owns 8 wave-uniform queries
// (coeffs broadcast to SGPRs). Lanes scan LDS tile interleaved (lane + 64j).
// Inner loop keeps top-3 as packed u32 keys: high bits = d^2 float bits
// (d^2 >= 0 so unsigned order == float order), low 7 bits = j (idx>>6);
// lane supplies idx low 6 bits. Sorted insert = v_min_u32 + 2x v_med3_u32.
// Butterfly merge across lanes carries expanded indices.

#define NTHREADS 256
#define TILE 1024
#define QPW 8
#define QPB 32
#define NJ (TILE / 64)
#define KEYMASK 0xFFFFFF80u

__device__ __forceinline__ unsigned med3u(unsigned x, unsigned a, unsigned b) {
  unsigned r;
  asm("v_med3_u32 %0, %1, %2, %3" : "=v"(r) : "v"(x), "v"(a), "v"(b));
  return r;
}

__device__ __forceinline__ float sbcast(float v) {
  return __int_as_float(__builtin_amdgcn_readfirstlane(__float_as_int(v)));
}

// merge sorted triple (a*, idx x*) with sorted triple (b*, idx y*): lowest 3.
__device__ __forceinline__ void cmerge(unsigned& a0, unsigned& a1, unsigned& a2,
                                       unsigned& x0, unsigned& x1, unsigned& x2,
                                       unsigned b0, unsigned b1, unsigned b2,
                                       unsigned y0, unsigned y1, unsigned y2) {
  const bool c0 = b0 < a0;
  const unsigned lo0k = c0 ? b0 : a0, lo0i = c0 ? y0 : x0;
  const unsigned hi0k = c0 ? a0 : b0, hi0i = c0 ? x0 : y0;
  const bool c1 = b1 < a1;
  const unsigned lo1k = c1 ? b1 : a1, lo1i = c1 ? y1 : x1;
  const unsigned hi1k = c1 ? a1 : b1, hi1i = c1 ? x1 : y1;
  const bool c2 = b2 < a2;
  const unsigned lo2k = c2 ? b2 : a2, lo2i = c2 ? y2 : x2;
  const bool c3 = hi0k < lo1k;
  const unsigned o1k = c3 ? hi0k : lo1k, o1i = c3 ? hi0i : lo1i;
  const unsigned tk = c3 ? lo1k : hi0k, ti = c3 ? lo1i : hi0i;
  const bool c4 = tk < lo2k;
  a0 = lo0k; x0 = lo0i;
  a1 = o1k;  x1 = o1i;
  a2 = c4 ? tk : lo2k;
  x2 = c4 ? ti : lo2i;
}

__global__ __launch_bounds__(NTHREADS) void pointwarp_kernel(
    const float* __restrict__ pos1,
    const float* __restrict__ pos2,
    const float* __restrict__ flow1,
    float* __restrict__ out,
    int N) {
  const int b = blockIdx.y;
  const int qbase = blockIdx.x * QPB;
  const int tid = threadIdx.x;
  const int lane = tid & 63;
  const int wav = tid >> 6;

  const float* p1 = pos1 + (size_t)b * 3 * N;
  const float* p2 = pos2 + (size_t)b * 3 * N;
  const float* f1 = flow1 + (size_t)b * 3 * N;

  // wave-uniform query coefficients in SGPRs: metric d2 = |k|^2 - 2q.k + |q|^2
  float na[QPW], nb_[QPW], nc[QPW], qq[QPW];
#pragma unroll
  for (int r = 0; r < QPW; ++r) {
    const int qi = qbase + wav * QPW + r;
    const float qx = p2[qi], qy = p2[N + qi], qz = p2[2 * N + qi];
    na[r] = sbcast(-2.0f * qx);
    nb_[r] = sbcast(-2.0f * qy);
    nc[r] = sbcast(-2.0f * qz);
    qq[r] = sbcast(fmaf(qx, qx, fmaf(qy, qy, qz * qz)));
  }

  __shared__ float4 tile[TILE];  // {kx,ky,kz,|k|^2}
  __shared__ int finals[QPB][3];

  unsigned k0[QPW], k1[QPW], k2[QPW];
#pragma unroll
  for (int r = 0; r < QPW; ++r) { k0[r] = 0xFFFFFFFFu; k1[r] = 0xFFFFFFFFu; k2[r] = 0xFFFFFFFFu; }

  for (int t = 0; t < N; t += TILE) {
    __syncthreads();
#pragma unroll
    for (int u = 0; u < TILE / NTHREADS; ++u) {
      const int j = u * NTHREADS + tid;
      const int g = t + j;
      const float kx = p1[g] + f1[g];
      const float ky = p1[N + g] + f1[N + g];
      const float kz = p1[2 * N + g] + f1[2 * N + g];
      tile[j] = make_float4(kx, ky, kz, fmaf(kx, kx, fmaf(ky, ky, kz * kz)));
    }
    __syncthreads();

#pragma unroll 4
    for (int j = 0; j < NJ; ++j) {
      const float4 k = tile[j * 64 + lane];
      const unsigned jj = (unsigned)((t + j * 64) >> 6);  // wave-uniform, 7 bits
#pragma unroll
      for (int r = 0; r < QPW; ++r) {
        const float m = fmaf(na[r], k.x, fmaf(nb_[r], k.y, fmaf(nc[r], k.z, k.w)));
        const float d2 = fmaxf(m + qq[r], 0.0f);
        const unsigned key = (__float_as_uint(d2) & KEYMASK) | jj;
        const unsigned o0 = k0[r], o1 = k1[r];
        k0[r] = key < o0 ? key : o0;         // v_min_u32
        k1[r] = med3u(key, o0, o1);          // sorted-insert slots 1,2
        k2[r] = med3u(key, o1, k2[r]);
      }
    }
  }

  // expand full indices: idx = (j7 << 6) | lane
  unsigned i0[QPW], i1[QPW], i2[QPW];
#pragma unroll
  for (int r = 0; r < QPW; ++r) {
    i0[r] = ((k0[r] & 0x7Fu) << 6) | (unsigned)lane;
    i1[r] = ((k1[r] & 0x7Fu) << 6) | (unsigned)lane;
    i2[r] = ((k2[r] & 0x7Fu) << 6) | (unsigned)lane;
  }

  // butterfly merge across the wave (compound: compare keys, carry idx)
#pragma unroll
  for (int mask = 32; mask >= 1; mask >>= 1) {
#pragma unroll
    for (int r = 0; r < QPW; ++r) {
      const unsigned b0 = __shfl_xor(k0[r], mask, 64);
      const unsigned b1 = __shfl_xor(k1[r], mask, 64);
      const unsigned b2 = __shfl_xor(k2[r], mask, 64);
      const unsigned y0 = __shfl_xor(i0[r], mask, 64);
      const unsigned y1 = __shfl_xor(i1[r], mask, 64);
      const unsigned y2 = __shfl_xor(i2[r], mask, 64);
      cmerge(k0[r], k1[r], k2[r], i0[r], i1[r], i2[r], b0, b1, b2, y0, y1, y2);
    }
  }

  if (lane == 0) {
#pragma unroll
    for (int r = 0; r < QPW; ++r) {
      const int q = wav * QPW + r;
      finals[q][0] = (int)i0[r];
      finals[q][1] = (int)i1[r];
      finals[q][2] = (int)i2[r];
    }
  }
  __syncthreads();

  if (tid < QPB) {
    const int qi = qbase + tid;
    const float qx = p2[qi], qy = p2[N + qi], qz = p2[2 * N + qi];

    float w[3], gfx[3], gfy[3], gfz[3];
    float wsum = 0.0f;
#pragma unroll
    for (int r = 0; r < 3; ++r) {
      const int idx = finals[tid][r];
      const float fx = f1[idx], fy = f1[N + idx], fz = f1[2 * N + idx];
      const float kx = p1[idx] + fx;
      const float ky = p1[N + idx] + fy;
      const float kz = p1[2 * N + idx] + fz;
      const float dx = kx - qx, dy = ky - qy, dz = kz - qz;
      float d = sqrtf(dx * dx + dy * dy + dz * dz);
      d = fmaxf(d, 1e-10f);
      const float inv = 1.0f / d;
      w[r] = inv; wsum += inv;
      gfx[r] = fx; gfy[r] = fy; gfz[r] = fz;
    }
    const float invw = 1.0f / wsum;
    float ox = 0.0f, oy = 0.0f, oz = 0.0f;
#pragma unroll
    for (int r = 0; r < 3; ++r) {
      const float ww = w[r] * invw;
      ox = fmaf(ww, gfx[r], ox);
      oy = fmaf(ww, gfy[r], oy);
      oz = fmaf(ww, gfz[r], oz);
    }
    ox = qx - ox; oy = qy - oy; oz = qz - oz;
    ox = fminf(fmaxf(ox, -10.0f), 10.0f);
    oy = fminf(fmaxf(oy, -10.0f), 10.0f);
    oz = fminf(fmaxf(oz, -10.0f), 10.0f);
    float* o = out + (size_t)b * 3 * N;
    o[qi] = ox;
    o[N + qi] = oy;
    o[2 * N + qi] = oz;
  }
}

extern "C" void kernel_launch(void* const* d_in, const int* in_sizes, int n_in,
                              void* d_out, int out_size, void* d_ws, size_t ws_size,
                              hipStream_t stream) {
  const float* pos1 = (const float*)d_in[0];
  const float* pos2 = (const float*)d_in[1];
  const float* flow1 = (const float*)d_in[2];
  float* out = (float*)d_out;

  const int B = 4;
  const int N = in_sizes[0] / (B * 3);  // 8192

  dim3 grid(N / QPB, B);
  dim3 block(NTHREADS);
  pointwarp_kernel<<<grid, block, 0, stream>>>(pos1, pos2, flow1, out, N);
}

// Round 4
// 78.461 us; speedup vs baseline: 1.8894x; 1.0399x over previous
//
#include <hip/hip_runtime.h>
#include <math.h>

// PointWarping: B=4, C=3, N=8192 fp32 brute-force 3-NN + IDW flow warp.
// Block = 512 threads = 8 waves; each wave owns 4 wave-uniform queries
// (coeffs in SGPRs); lanes scan LDS tile interleaved (lane + 64j).
// Top-3 as packed u32 keys: high 25 bits = float bits of (d^2 + const_bias)
// (positive -> unsigned order == float order), low 7 bits = j-group (idx>>6);
// lane id supplies idx low 6 bits. Sorted insert = v_min_u32 + 2x v_med3_u32.
// Per-query constant bias C = 1.0625*|q|^2 + 2^-7 keeps keys > 0 without an
// fmax, and constant shifts preserve ordering. Butterfly shuffle merge.

#define NTHREADS 512
#define TILE 1024
#define QPW 4                      // queries per wave
#define QPB 32                     // queries per block (8 waves)
#define NJ (TILE / 64)
#define KEYMASK 0xFFFFFF80u

__device__ __forceinline__ unsigned med3u(unsigned x, unsigned a, unsigned b) {
  unsigned r;
  asm("v_med3_u32 %0, %1, %2, %3" : "=v"(r) : "v"(x), "v"(a), "v"(b));
  return r;
}

__device__ __forceinline__ float sbcast(float v) {
  return __int_as_float(__builtin_amdgcn_readfirstlane(__float_as_int(v)));
}

// merge sorted key-triple a (idx x) with sorted triple b (idx y): keep low 3.
__device__ __forceinline__ void cmerge(unsigned& a0, unsigned& a1, unsigned& a2,
                                       unsigned& x0, unsigned& x1, unsigned& x2,
                                       unsigned b0, unsigned b1, unsigned b2,
                                       unsigned y0, unsigned y1, unsigned y2) {
  const bool c0 = b0 < a0;
  const unsigned lo0k = c0 ? b0 : a0, lo0i = c0 ? y0 : x0;
  const unsigned hi0k = c0 ? a0 : b0, hi0i = c0 ? x0 : y0;
  const bool c1 = b1 < a1;
  const unsigned lo1k = c1 ? b1 : a1, lo1i = c1 ? y1 : x1;
  const unsigned hi1k = c1 ? a1 : b1, hi1i = c1 ? x1 : y1;
  const bool c2 = b2 < a2;
  const unsigned lo2k = c2 ? b2 : a2, lo2i = c2 ? y2 : x2;
  const bool c3 = hi0k < lo1k;
  const unsigned o1k = c3 ? hi0k : lo1k, o1i = c3 ? hi0i : lo1i;
  const unsigned tk = c3 ? lo1k : hi0k, ti = c3 ? lo1i : hi0i;
  const bool c4 = tk < lo2k;
  a0 = lo0k; x0 = lo0i;
  a1 = o1k;  x1 = o1i;
  a2 = c4 ? tk : lo2k;
  x2 = c4 ? ti : lo2i;
}

__global__ __launch_bounds__(NTHREADS) void pointwarp_kernel(
    const float* __restrict__ pos1,
    const float* __restrict__ pos2,
    const float* __restrict__ flow1,
    float* __restrict__ out,
    int N) {
  const int b = blockIdx.y;
  const int qbase = blockIdx.x * QPB;
  const int tid = threadIdx.x;
  const int lane = tid & 63;
  const int wav = tid >> 6;  // 0..7

  const float* p1 = pos1 + (size_t)b * 3 * N;
  const float* p2 = pos2 + (size_t)b * 3 * N;
  const float* f1 = flow1 + (size_t)b * 3 * N;

  // wave-uniform query coefficients in SGPRs.
  // keyval = |k|^2 - 2 q.k + C  ==  d^2 + (C - |q|^2)  > 0, order-preserving.
  float na[QPW], nb_[QPW], nc[QPW], cc[QPW];
#pragma unroll
  for (int r = 0; r < QPW; ++r) {
    const int qi = qbase + wav * QPW + r;
    const float qx = p2[qi], qy = p2[N + qi], qz = p2[2 * N + qi];
    na[r] = sbcast(-2.0f * qx);
    nb_[r] = sbcast(-2.0f * qy);
    nc[r] = sbcast(-2.0f * qz);
    const float qq = fmaf(qx, qx, fmaf(qy, qy, qz * qz));
    cc[r] = sbcast(fmaf(qq, 1.0625f, 0.0078125f));
  }

  __shared__ float4 tile[TILE];  // {kx,ky,kz,|k|^2}
  __shared__ int finals[QPB][3];

  unsigned k0[QPW], k1[QPW], k2[QPW];
#pragma unroll
  for (int r = 0; r < QPW; ++r) { k0[r] = 0xFFFFFFFFu; k1[r] = 0xFFFFFFFFu; k2[r] = 0xFFFFFFFFu; }

  for (int t = 0; t < N; t += TILE) {
    __syncthreads();
#pragma unroll
    for (int u = 0; u < TILE / NTHREADS; ++u) {
      const int j = u * NTHREADS + tid;
      const int g = t + j;
      const float kx = p1[g] + f1[g];
      const float ky = p1[N + g] + f1[N + g];
      const float kz = p1[2 * N + g] + f1[2 * N + g];
      tile[j] = make_float4(kx, ky, kz, fmaf(kx, kx, fmaf(ky, ky, kz * kz)));
    }
    __syncthreads();

#pragma unroll 4
    for (int j = 0; j < NJ; ++j) {
      const float4 k = tile[j * 64 + lane];
      const unsigned jj = (unsigned)((t + j * 64) >> 6);  // wave-uniform, 7 bits
#pragma unroll
      for (int r = 0; r < QPW; ++r) {
        const float m = fmaf(na[r], k.x, fmaf(nb_[r], k.y, fmaf(nc[r], k.z, k.w)));
        const float v = m + cc[r];                       // > 0 by construction
        const unsigned key = (__float_as_uint(v) & KEYMASK) | jj;  // v_and_or_b32
        const unsigned o0 = k0[r], o1 = k1[r];
        k0[r] = key < o0 ? key : o0;  // v_min_u32
        k1[r] = med3u(key, o0, o1);
        k2[r] = med3u(key, o1, k2[r]);
      }
    }
  }

  // expand full indices: idx = (j7 << 6) | lane
  unsigned i0[QPW], i1[QPW], i2[QPW];
#pragma unroll
  for (int r = 0; r < QPW; ++r) {
    i0[r] = ((k0[r] & 0x7Fu) << 6) | (unsigned)lane;
    i1[r] = ((k1[r] & 0x7Fu) << 6) | (unsigned)lane;
    i2[r] = ((k2[r] & 0x7Fu) << 6) | (unsigned)lane;
  }

  // butterfly merge across the 64 lanes of the wave
#pragma unroll
  for (int mask = 32; mask >= 1; mask >>= 1) {
#pragma unroll
    for (int r = 0; r < QPW; ++r) {
      const unsigned b0 = __shfl_xor(k0[r], mask, 64);
      const unsigned b1 = __shfl_xor(k1[r], mask, 64);
      const unsigned b2 = __shfl_xor(k2[r], mask, 64);
      const unsigned y0 = __shfl_xor(i0[r], mask, 64);
      const unsigned y1 = __shfl_xor(i1[r], mask, 64);
      const unsigned y2 = __shfl_xor(i2[r], mask, 64);
      cmerge(k0[r], k1[r], k2[r], i0[r], i1[r], i2[r], b0, b1, b2, y0, y1, y2);
    }
  }

  if (lane == 0) {
#pragma unroll
    for (int r = 0; r < QPW; ++r) {
      const int q = wav * QPW + r;
      finals[q][0] = (int)i0[r];
      finals[q][1] = (int)i1[r];
      finals[q][2] = (int)i2[r];
    }
  }
  __syncthreads();

  if (tid < QPB) {
    const int qi = qbase + tid;
    const float qx = p2[qi], qy = p2[N + qi], qz = p2[2 * N + qi];

    float w[3], gfx[3], gfy[3], gfz[3];
    float wsum = 0.0f;
#pragma unroll
    for (int r = 0; r < 3; ++r) {
      const int idx = finals[tid][r];
      const float fx = f1[idx], fy = f1[N + idx], fz = f1[2 * N + idx];
      const float kx = p1[idx] + fx;
      const float ky = p1[N + idx] + fy;
      const float kz = p1[2 * N + idx] + fz;
      const float dx = kx - qx, dy = ky - qy, dz = kz - qz;
      float d = sqrtf(dx * dx + dy * dy + dz * dz);
      d = fmaxf(d, 1e-10f);
      const float inv = 1.0f / d;
      w[r] = inv; wsum += inv;
      gfx[r] = fx; gfy[r] = fy; gfz[r] = fz;
    }
    const float invw = 1.0f / wsum;
    float ox = 0.0f, oy = 0.0f, oz = 0.0f;
#pragma unroll
    for (int r = 0; r < 3; ++r) {
      const float ww = w[r] * invw;
      ox = fmaf(ww, gfx[r], ox);
      oy = fmaf(ww, gfy[r], oy);
      oz = fmaf(ww, gfz[r], oz);
    }
    ox = qx - ox; oy = qy - oy; oz = qz - oz;
    ox = fminf(fmaxf(ox, -10.0f), 10.0f);
    oy = fminf(fmaxf(oy, -10.0f), 10.0f);
    oz = fminf(fmaxf(oz, -10.0f), 10.0f);
    float* o = out + (size_t)b * 3 * N;
    o[qi] = ox;
    o[N + qi] = oy;
    o[2 * N + qi] = oz;
  }
}

extern "C" void kernel_launch(void* const* d_in, const int* in_sizes, int n_in,
                              void* d_out, int out_size, void* d_ws, size_t ws_size,
                              hipStream_t stream) {
  const float* pos1 = (const float*)d_in[0];
  const float* pos2 = (const float*)d_in[1];
  const float* flow1 = (const float*)d_in[2];
  float* out = (float*)d_out;

  const int B = 4;
  const int N = in_sizes[0] / (B * 3);  // 8192

  dim3 grid(N / QPB, B);
  dim3 block(NTHREADS);
  pointwarp_kernel<<<grid, block, 0, stream>>>(pos1, pos2, flow1, out, N);
}